// Round 9
// baseline (8931.389 us; speedup 1.0000x reference)
//
#include <hip/hip_runtime.h>
#include <hip/hip_fp16.h>
#include <cstddef>
#include <cstdint>

#define B_  256
#define T_  512
#define D_  128
#define H_  256
#define G3_ 768
#define C_  10

__device__ __forceinline__ float sigmoid_f(float x) {
    return 1.0f / (1.0f + __expf(-x));
}
__device__ __forceinline__ float tanh_f(float x) {
    return 1.0f - 2.0f / (__expf(2.0f * x) + 1.0f);
}

__device__ __forceinline__ unsigned int packh2(float a, float b) {
    unsigned short lo = __half_as_ushort(__float2half(a));   // k even -> lo16
    unsigned short hi = __half_as_ushort(__float2half(b));   // k odd  -> hi16
    return (unsigned int)lo | ((unsigned int)hi << 16);
}

// ---------------------------------------------------------------------------
// Pack Whh[3H][H] fp32 -> f16 stream layout for the 512-thread scan.
// Scan lane t: wave w=t>>6, lane l=t&63, j=w*32+(l&31), k-half q=(l>>5)&1.
// Wl[(g*16+i)*512 + t] = uint4 of 8 f16 weights: gate g, k = q*128+8i+0..7.
// grid: 48 blocks x 512 threads. 393,216 B per layer.
// ---------------------------------------------------------------------------
__global__ void k_pack_whh(const float* __restrict__ Whh, uint4* __restrict__ Wl) {
    const int g = blockIdx.x >> 4;
    const int i = blockIdx.x & 15;
    const int t = threadIdx.x;
    const int j = ((t >> 6) << 5) + (t & 31);
    const int q = (t >> 5) & 1;
    const int kb = q * 128 + 8 * i;
    const float* row = Whh + (size_t)(g * H_ + j) * H_;
    uint4 u;
    u.x = packh2(row[kb + 0], row[kb + 1]);
    u.y = packh2(row[kb + 2], row[kb + 3]);
    u.z = packh2(row[kb + 4], row[kb + 5]);
    u.w = packh2(row[kb + 6], row[kb + 7]);
    Wl[(size_t)blockIdx.x * 512 + t] = u;
}

// ---------------------------------------------------------------------------
// C[M,N] = A[M,K] @ W[N,K]^T + bias[N]  (fp32 NT, chunk-major A rows).
// ---------------------------------------------------------------------------
__global__ __launch_bounds__(256, 2) void k_gemm_nt_bias(
    const float* __restrict__ A, long Abstride,
    const float* __restrict__ W,
    const float* __restrict__ bias, float* __restrict__ C,
    int N, int K, int tcShift)
{
    __shared__ float As[16][128];
    __shared__ float Ws[16][64];
    const int tid = threadIdx.x;
    const int tx = tid & 15;
    const int ty = tid >> 4;
    const int m0 = blockIdx.y * 128;
    const int n0 = blockIdx.x * 64;
    const int arow = tid >> 1;
    const int ak   = (tid & 1) * 8;
    const int wrow = tid >> 2;
    const int wk   = (tid & 3) * 4;

    const int mask = (1 << tcShift) - 1;
    const int mg = m0 + arow;
    const float* Arow = A + (size_t)(mg >> tcShift) * Abstride + (size_t)(mg & mask) * K;
    const float* Wrow = W + (size_t)(n0 + wrow) * K;

    float acc[8][4] = {};

    for (int k0 = 0; k0 < K; k0 += 16) {
        float4 a0 = *(const float4*)&Arow[k0 + ak];
        float4 a1 = *(const float4*)&Arow[k0 + ak + 4];
        float4 wv = *(const float4*)&Wrow[k0 + wk];
        __syncthreads();
        As[ak + 0][arow] = a0.x; As[ak + 1][arow] = a0.y;
        As[ak + 2][arow] = a0.z; As[ak + 3][arow] = a0.w;
        As[ak + 4][arow] = a1.x; As[ak + 5][arow] = a1.y;
        As[ak + 6][arow] = a1.z; As[ak + 7][arow] = a1.w;
        Ws[wk + 0][wrow] = wv.x; Ws[wk + 1][wrow] = wv.y;
        Ws[wk + 2][wrow] = wv.z; Ws[wk + 3][wrow] = wv.w;
        __syncthreads();
#pragma unroll
        for (int kk = 0; kk < 16; kk++) {
            float a8[8], b4[4];
            *(float4*)&a8[0] = *(const float4*)&As[kk][ty * 8];
            *(float4*)&a8[4] = *(const float4*)&As[kk][ty * 8 + 4];
            *(float4*)&b4[0] = *(const float4*)&Ws[kk][tx * 4];
#pragma unroll
            for (int ii = 0; ii < 8; ii++)
#pragma unroll
                for (int jj = 0; jj < 4; jj++)
                    acc[ii][jj] = fmaf(a8[ii], b4[jj], acc[ii][jj]);
        }
    }

    float b4[4];
#pragma unroll
    for (int jj = 0; jj < 4; jj++) b4[jj] = bias[n0 + tx * 4 + jj];
#pragma unroll
    for (int ii = 0; ii < 8; ii++) {
        float4 v;
        v.x = acc[ii][0] + b4[0];
        v.y = acc[ii][1] + b4[1];
        v.z = acc[ii][2] + b4[2];
        v.w = acc[ii][3] + b4[3];
        *(float4*)&C[(size_t)(m0 + ty * 8 + ii) * N + n0 + tx * 4] = v;
    }
}

// ---------------------------------------------------------------------------
// Spill-free streaming scan. Block = 4 batch rows, 512 thr (8 waves).
// Lane owns (j, k-half q) and streams its 48 uint4 f16 weights from L2 every
// step (393 KB/CU/step -- R3 proved clean streams are ~100% L2-hit; the
// R4-R8 disasters were all scratch spills, detectable as GB-scale FETCH).
// Working set ~96 VGPRs < the 65536/blockDim=128 allocator cap -> no spill.
// 84 KB static LDS pins 1 block/CU (2 blocks would need 168 KB > 160 KB).
// Per step: VALU ~6.1K cyc/SIMD ~= VMEM bytes 6.5K cyc -> ~2.9 us/step.
// ---------------------------------------------------------------------------
__device__ __forceinline__ void dot8h(float& acc, const uint4& u,
                                      const float4& hA, const float4& hB) {
    const __half2 p0 = *reinterpret_cast<const __half2*>(&u.x);
    const __half2 p1 = *reinterpret_cast<const __half2*>(&u.y);
    const __half2 p2 = *reinterpret_cast<const __half2*>(&u.z);
    const __half2 p3 = *reinterpret_cast<const __half2*>(&u.w);
    acc = fmaf(__low2float(p0),  hA.x, acc);
    acc = fmaf(__high2float(p0), hA.y, acc);
    acc = fmaf(__low2float(p1),  hA.z, acc);
    acc = fmaf(__high2float(p1), hA.w, acc);
    acc = fmaf(__low2float(p2),  hB.x, acc);
    acc = fmaf(__high2float(p2), hB.y, acc);
    acc = fmaf(__low2float(p3),  hB.z, acc);
    acc = fmaf(__high2float(p3), hB.w, acc);
}

__device__ __forceinline__ void gru_scan_core(
    const float* __restrict__ gi,      // + b0*Tc*G3   [4 rows][Tc][3H]
    const uint4* __restrict__ Wl,      // [48][512]
    const float* __restrict__ bhh,
    float* __restrict__ h_state,       // + b0*H
    float* __restrict__ out_seq,       // + b0*Tc*H or nullptr
    int Tc, int initZero,
    float (&hbuf)[2][4][H_])
{
    const int t = threadIdx.x;
    const int j = ((t >> 6) << 5) + (t & 31);
    const int q = (t >> 5) & 1;
    const int kb = q * 128;
    const bool lead = (q == 0);

    const float br = bhh[j];
    const float bz = bhh[H_ + j];
    const float bn = bhh[2 * H_ + j];

    if (lead) {
#pragma unroll
        for (int r = 0; r < 4; r++)
            hbuf[0][r][j] = initZero ? 0.0f : h_state[(size_t)r * H_ + j];
    }
    __syncthreads();

    const uint4* wlt = Wl + t;

    int cur = 0;
    for (int tt = 0; tt < Tc; ++tt) {
        // gi loads issued at step top (lead lanes); consumed ~6K cycles later
        // after the k-loop -> latency fully hidden inside the step.
        float gc[4][3];
        if (lead) {
#pragma unroll
            for (int r = 0; r < 4; r++) {
                const float* gp = gi + ((size_t)r * Tc + tt) * G3_;
                gc[r][0] = gp[j];
                gc[r][1] = gp[H_ + j];
                gc[r][2] = gp[2 * H_ + j];
            }
        }

        float ar[4] = {}, az[4] = {}, an[4] = {};
#pragma unroll
        for (int i = 0; i < 16; i++) {
            uint4 wr = wlt[(size_t)(0 * 16 + i) * 512];
            uint4 wz = wlt[(size_t)(1 * 16 + i) * 512];
            uint4 wn = wlt[(size_t)(2 * 16 + i) * 512];
#pragma unroll
            for (int r = 0; r < 4; r++) {
                float4 hA = *(const float4*)&hbuf[cur][r][kb + 8 * i];
                float4 hB = *(const float4*)&hbuf[cur][r][kb + 8 * i + 4];
                dot8h(ar[r], wr, hA, hB);
                dot8h(az[r], wz, hA, hB);
                dot8h(an[r], wn, hA, hB);
            }
        }

#pragma unroll
        for (int r = 0; r < 4; r++) {
            ar[r] += __shfl_xor(ar[r], 32, 64);
            az[r] += __shfl_xor(az[r], 32, 64);
            an[r] += __shfl_xor(an[r], 32, 64);
        }

        if (lead) {
#pragma unroll
            for (int r = 0; r < 4; r++) {
                float rr = sigmoid_f(gc[r][0] + ar[r] + br);
                float zz = sigmoid_f(gc[r][1] + az[r] + bz);
                float nn = tanh_f(gc[r][2] + rr * (an[r] + bn)); // bhh_n in r-gate
                float hn = (1.0f - zz) * nn + zz * hbuf[cur][r][j];
                hbuf[cur ^ 1][r][j] = hn;
                if (out_seq)
                    out_seq[((size_t)r * Tc + tt) * H_ + j] = hn;
                if (tt == Tc - 1)
                    h_state[(size_t)r * H_ + j] = hn;
            }
        }
        __syncthreads();
        cur ^= 1;
    }
}

// Fused layer-pipelined scan: blocks 0..63 -> layer0 chunk c (4 rows each),
// blocks 64..127 -> layer1 chunk c-1. 84 KB static LDS -> 1 block/CU.
__global__ __launch_bounds__(512) void k_gru_scan_fused(
    const float* __restrict__ gi0, const uint4* __restrict__ wl0,
    const float* __restrict__ bhh0, float* __restrict__ hst0,
    float* __restrict__ h1c,
    const float* __restrict__ gi1, const uint4* __restrict__ wl1,
    const float* __restrict__ bhh1, float* __restrict__ hst1,
    int Tc, int do0, int do1, int init0, int init1)
{
    __shared__ __align__(16) float hbuf[2][4][H_];        // 8 KB
    __shared__ float occupancy_pad[19456];                 // 76 KB -> 1 blk/CU
    if (Tc < 0) {   // never true at runtime; keeps the pad allocated
        occupancy_pad[threadIdx.x] = (float)do0;
        hbuf[0][0][threadIdx.x & 255] = occupancy_pad[(threadIdx.x * 7) & 19455];
    }

    const int blk = blockIdx.x;
    if (blk < 64) {
        if (!do0) return;
        const int b0 = blk * 4;
        gru_scan_core(gi0 + (size_t)b0 * Tc * G3_, wl0, bhh0,
                      hst0 + (size_t)b0 * H_, h1c + (size_t)b0 * Tc * H_,
                      Tc, init0, hbuf);
    } else {
        if (!do1) return;
        const int b0 = (blk - 64) * 4;
        gru_scan_core(gi1 + (size_t)b0 * Tc * G3_, wl1, bhh1,
                      hst1 + (size_t)b0 * H_, nullptr,
                      Tc, init1, hbuf);
    }
}

// ---------------------------------------------------------------------------
__global__ void k_fc(const float* __restrict__ h, const float* __restrict__ Wfc,
                     const float* __restrict__ bfc, float* __restrict__ out)
{
    int idx = blockIdx.x * blockDim.x + threadIdx.x;
    if (idx >= B_ * C_) return;
    int b = idx / C_, c = idx % C_;
    const float* hp = h + (size_t)b * H_;
    const float* wp = Wfc + (size_t)c * H_;
    float s = bfc[c];
#pragma unroll 4
    for (int k = 0; k < H_; k++) s = fmaf(hp[k], wp[k], s);
    out[idx] = s;
}

// ---------------------------------------------------------------------------
extern "C" void kernel_launch(void* const* d_in, const int* in_sizes, int n_in,
                              void* d_out, int out_size, void* d_ws, size_t ws_size,
                              hipStream_t stream)
{
    const float* x    = (const float*)d_in[0];
    const float* Wih0 = (const float*)d_in[1];
    const float* Whh0 = (const float*)d_in[2];
    const float* bih0 = (const float*)d_in[3];
    const float* bhh0 = (const float*)d_in[4];
    const float* Wih1 = (const float*)d_in[5];
    const float* Whh1 = (const float*)d_in[6];
    const float* bih1 = (const float*)d_in[7];
    const float* bhh1 = (const float*)d_in[8];
    const float* Wfc  = (const float*)d_in[9];
    const float* bfc  = (const float*)d_in[10];
    float* out = (float*)d_out;

    const size_t wlBytes = (size_t)48 * 512 * sizeof(uint4);   // 393,216 B

    // ---- largest power-of-two T-chunk that fits ws_size -------------------
    const size_t fixedB = 2 * wlBytes + 2 * (size_t)B_ * H_ * 4 + 8192;
    int Tc = 128, tcShift = 7;
    while (Tc > 1) {
        size_t need = fixedB
                    + 2 * (size_t)B_ * Tc * G3_ * 4    // gi0, gi1 chunks
                    + (size_t)B_ * Tc * H_ * 4;        // h1 chunk
        if (need <= ws_size) break;
        Tc >>= 1; tcShift--;
    }
    const int nChunks = T_ / Tc;

    char* ws = (char*)d_ws;
    size_t off = 0;
    auto alloc = [&](size_t bytes) { char* p = ws + off; off += (bytes + 255) & ~(size_t)255; return p; };
    float* gi0  = (float*)alloc((size_t)B_ * Tc * G3_ * 4);
    float* gi1  = (float*)alloc((size_t)B_ * Tc * G3_ * 4);
    float* h1c  = (float*)alloc((size_t)B_ * Tc * H_ * 4);
    uint4* wl0  = (uint4*)alloc(wlBytes);
    uint4* wl1  = (uint4*)alloc(wlBytes);
    float* hst0 = (float*)alloc((size_t)B_ * H_ * 4);
    float* hst1 = (float*)alloc((size_t)B_ * H_ * 4);

    k_pack_whh<<<48, 512, 0, stream>>>(Whh0, wl0);
    k_pack_whh<<<48, 512, 0, stream>>>(Whh1, wl1);

    const dim3 ggrid(G3_ / 64, (B_ * Tc) / 128);

    // software pipeline: fused launch c runs scan0(c) and scan1(c-1)
    k_gemm_nt_bias<<<ggrid, 256, 0, stream>>>(
        x, (long)T_ * D_, Wih0, bih0, gi0, G3_, D_, tcShift);
    k_gru_scan_fused<<<128, 512, 0, stream>>>(
        gi0, wl0, bhh0, hst0, h1c, gi1, wl1, bhh1, hst1,
        Tc, 1, 0, 1, 0);

    for (int c = 1; c < nChunks; ++c) {
        k_gemm_nt_bias<<<ggrid, 256, 0, stream>>>(
            h1c, (long)Tc * H_, Wih1, bih1, gi1, G3_, H_, tcShift);  // chunk c-1
        k_gemm_nt_bias<<<ggrid, 256, 0, stream>>>(
            x + (size_t)c * Tc * D_, (long)T_ * D_, Wih0, bih0, gi0,
            G3_, D_, tcShift);                                        // chunk c
        k_gru_scan_fused<<<128, 512, 0, stream>>>(
            gi0, wl0, bhh0, hst0, h1c, gi1, wl1, bhh1, hst1,
            Tc, 1, 1, 0, c == 1);
    }

    k_gemm_nt_bias<<<ggrid, 256, 0, stream>>>(
        h1c, (long)Tc * H_, Wih1, bih1, gi1, G3_, H_, tcShift);      // last chunk
    k_gru_scan_fused<<<128, 512, 0, stream>>>(
        gi0, wl0, bhh0, hst0, h1c, gi1, wl1, bhh1, hst1,
        Tc, 0, 1, 0, nChunks == 1);

    k_fc<<<10, 256, 0, stream>>>(hst1, Wfc, bfc, out);
}

// Round 10
// 7094.280 us; speedup vs baseline: 1.2590x; 1.2590x over previous
//
#include <hip/hip_runtime.h>
#include <hip/hip_fp16.h>
#include <cstddef>
#include <cstdint>

#define B_  256
#define T_  512
#define D_  128
#define H_  256
#define G3_ 768
#define C_  10

__device__ __forceinline__ float sigmoid_f(float x) {
    return 1.0f / (1.0f + __expf(-x));
}
__device__ __forceinline__ float tanh_f(float x) {
    return 1.0f - 2.0f / (__expf(2.0f * x) + 1.0f);
}

__device__ __forceinline__ unsigned int packh2(float a, float b) {
    unsigned short lo = __half_as_ushort(__float2half(a));   // k even -> lo16
    unsigned short hi = __half_as_ushort(__float2half(b));   // k odd  -> hi16
    return (unsigned int)lo | ((unsigned int)hi << 16);
}

// ---------------------------------------------------------------------------
// Pack Whh[3H][H] fp32 -> f16 stream layout for the 512-thread scan.
// Scan lane t: wave w=t>>6, lane l=t&63, j=w*32+(l&31), k-half q=(l>>5)&1.
// Wl[(g*16+i)*512 + t] = uint4 of 8 f16 weights: gate g, k = q*128+8i+0..7.
// grid: 48 blocks x 512 threads. 393,216 B per layer.
// ---------------------------------------------------------------------------
__global__ void k_pack_whh(const float* __restrict__ Whh, uint4* __restrict__ Wl) {
    const int g = blockIdx.x >> 4;
    const int i = blockIdx.x & 15;
    const int t = threadIdx.x;
    const int j = ((t >> 6) << 5) + (t & 31);
    const int q = (t >> 5) & 1;
    const int kb = q * 128 + 8 * i;
    const float* row = Whh + (size_t)(g * H_ + j) * H_;
    uint4 u;
    u.x = packh2(row[kb + 0], row[kb + 1]);
    u.y = packh2(row[kb + 2], row[kb + 3]);
    u.z = packh2(row[kb + 4], row[kb + 5]);
    u.w = packh2(row[kb + 6], row[kb + 7]);
    Wl[(size_t)blockIdx.x * 512 + t] = u;
}

// ---------------------------------------------------------------------------
// C[M,N] = A[M,K] @ W[N,K]^T + bias[N]  (fp32 NT, chunk-major A rows).
// ---------------------------------------------------------------------------
__global__ __launch_bounds__(256, 2) void k_gemm_nt_bias(
    const float* __restrict__ A, long Abstride,
    const float* __restrict__ W,
    const float* __restrict__ bias, float* __restrict__ C,
    int N, int K, int tcShift)
{
    __shared__ float As[16][128];
    __shared__ float Ws[16][64];
    const int tid = threadIdx.x;
    const int tx = tid & 15;
    const int ty = tid >> 4;
    const int m0 = blockIdx.y * 128;
    const int n0 = blockIdx.x * 64;
    const int arow = tid >> 1;
    const int ak   = (tid & 1) * 8;
    const int wrow = tid >> 2;
    const int wk   = (tid & 3) * 4;

    const int mask = (1 << tcShift) - 1;
    const int mg = m0 + arow;
    const float* Arow = A + (size_t)(mg >> tcShift) * Abstride + (size_t)(mg & mask) * K;
    const float* Wrow = W + (size_t)(n0 + wrow) * K;

    float acc[8][4] = {};

    for (int k0 = 0; k0 < K; k0 += 16) {
        float4 a0 = *(const float4*)&Arow[k0 + ak];
        float4 a1 = *(const float4*)&Arow[k0 + ak + 4];
        float4 wv = *(const float4*)&Wrow[k0 + wk];
        __syncthreads();
        As[ak + 0][arow] = a0.x; As[ak + 1][arow] = a0.y;
        As[ak + 2][arow] = a0.z; As[ak + 3][arow] = a0.w;
        As[ak + 4][arow] = a1.x; As[ak + 5][arow] = a1.y;
        As[ak + 6][arow] = a1.z; As[ak + 7][arow] = a1.w;
        Ws[wk + 0][wrow] = wv.x; Ws[wk + 1][wrow] = wv.y;
        Ws[wk + 2][wrow] = wv.z; Ws[wk + 3][wrow] = wv.w;
        __syncthreads();
#pragma unroll
        for (int kk = 0; kk < 16; kk++) {
            float a8[8], b4[4];
            *(float4*)&a8[0] = *(const float4*)&As[kk][ty * 8];
            *(float4*)&a8[4] = *(const float4*)&As[kk][ty * 8 + 4];
            *(float4*)&b4[0] = *(const float4*)&Ws[kk][tx * 4];
#pragma unroll
            for (int ii = 0; ii < 8; ii++)
#pragma unroll
                for (int jj = 0; jj < 4; jj++)
                    acc[ii][jj] = fmaf(a8[ii], b4[jj], acc[ii][jj]);
        }
    }

    float b4[4];
#pragma unroll
    for (int jj = 0; jj < 4; jj++) b4[jj] = bias[n0 + tx * 4 + jj];
#pragma unroll
    for (int ii = 0; ii < 8; ii++) {
        float4 v;
        v.x = acc[ii][0] + b4[0];
        v.y = acc[ii][1] + b4[1];
        v.z = acc[ii][2] + b4[2];
        v.w = acc[ii][3] + b4[3];
        *(float4*)&C[(size_t)(m0 + ty * 8 + ii) * N + n0 + tx * 4] = v;
    }
}

// ---------------------------------------------------------------------------
// TRUE-streaming scan. Block = 4 batch rows, 512 thr (8 waves).
// Lane owns (j, k-half q) and re-streams its 48 uint4 f16 weights from L2
// every step. CRITICAL: the weight base pointer is laundered through an
// empty asm at the top of every time step. Without it the compiler proves
// the loads loop-invariant, hoists them (192 regs), spills past the
// 65536/blockDim=128 VGPR cap, and re-reads scratch every step -- that was
// R4-R9's GB-scale FETCH_SIZE. R3's 99.8% L2 hit proves the shared-stream
// path works when loads actually stay in the loop.
// 84 KB static LDS pins 1 block/CU. h reads are half-wave-uniform ->
// LDS broadcast, conflict-free (R9: SQ_LDS_BANK_CONFLICT = 0).
// ---------------------------------------------------------------------------
__device__ __forceinline__ void dot8h(float& acc, const uint4& u,
                                      const float4& hA, const float4& hB) {
    const __half2 p0 = *reinterpret_cast<const __half2*>(&u.x);
    const __half2 p1 = *reinterpret_cast<const __half2*>(&u.y);
    const __half2 p2 = *reinterpret_cast<const __half2*>(&u.z);
    const __half2 p3 = *reinterpret_cast<const __half2*>(&u.w);
    acc = fmaf(__low2float(p0),  hA.x, acc);
    acc = fmaf(__high2float(p0), hA.y, acc);
    acc = fmaf(__low2float(p1),  hA.z, acc);
    acc = fmaf(__high2float(p1), hA.w, acc);
    acc = fmaf(__low2float(p2),  hB.x, acc);
    acc = fmaf(__high2float(p2), hB.y, acc);
    acc = fmaf(__low2float(p3),  hB.z, acc);
    acc = fmaf(__high2float(p3), hB.w, acc);
}

__device__ __forceinline__ void gru_scan_core(
    const float* __restrict__ gi,      // + b0*Tc*G3   [4 rows][Tc][3H]
    const uint4* __restrict__ Wl,      // [48][512]
    const float* __restrict__ bhh,
    float* __restrict__ h_state,       // + b0*H
    float* __restrict__ out_seq,       // + b0*Tc*H or nullptr
    int Tc, int initZero,
    float (&hbuf)[2][4][H_])
{
    const int t = threadIdx.x;
    const int j = ((t >> 6) << 5) + (t & 31);
    const int q = (t >> 5) & 1;
    const int kb = q * 128;
    const bool lead = (q == 0);

    const float br = bhh[j];
    const float bz = bhh[H_ + j];
    const float bn = bhh[2 * H_ + j];

    if (lead) {
#pragma unroll
        for (int r = 0; r < 4; r++)
            hbuf[0][r][j] = initZero ? 0.0f : h_state[(size_t)r * H_ + j];
    }
    __syncthreads();

    const uint4* wbase = Wl + t;

    int cur = 0;
    for (int tt = 0; tt < Tc; ++tt) {
        // ---- LICM barrier: address is opaque each step -> loads re-issue
        // from global (L2-shared) instead of hoist+spill to private scratch.
        const uint4* wlt = wbase;
        asm("" : "+v"(wlt));

        // gi loads issued at step top (lead lanes); consumed after the
        // k-loop ~6K cycles later -> L3 latency hidden inside the step.
        float gc[4][3];
        if (lead) {
#pragma unroll
            for (int r = 0; r < 4; r++) {
                const float* gp = gi + ((size_t)r * Tc + tt) * G3_;
                gc[r][0] = gp[j];
                gc[r][1] = gp[H_ + j];
                gc[r][2] = gp[2 * H_ + j];
            }
        }

        float ar[4] = {}, az[4] = {}, an[4] = {};
#pragma unroll
        for (int i = 0; i < 16; i++) {
            uint4 wr = wlt[(size_t)(0 * 16 + i) * 512];
            uint4 wz = wlt[(size_t)(1 * 16 + i) * 512];
            uint4 wn = wlt[(size_t)(2 * 16 + i) * 512];
#pragma unroll
            for (int r = 0; r < 4; r++) {
                float4 hA = *(const float4*)&hbuf[cur][r][kb + 8 * i];
                float4 hB = *(const float4*)&hbuf[cur][r][kb + 8 * i + 4];
                dot8h(ar[r], wr, hA, hB);
                dot8h(az[r], wz, hA, hB);
                dot8h(an[r], wn, hA, hB);
            }
        }

#pragma unroll
        for (int r = 0; r < 4; r++) {
            ar[r] += __shfl_xor(ar[r], 32, 64);
            az[r] += __shfl_xor(az[r], 32, 64);
            an[r] += __shfl_xor(an[r], 32, 64);
        }

        if (lead) {
#pragma unroll
            for (int r = 0; r < 4; r++) {
                float rr = sigmoid_f(gc[r][0] + ar[r] + br);
                float zz = sigmoid_f(gc[r][1] + az[r] + bz);
                float nn = tanh_f(gc[r][2] + rr * (an[r] + bn)); // bhh_n in r-gate
                float hn = (1.0f - zz) * nn + zz * hbuf[cur][r][j];
                hbuf[cur ^ 1][r][j] = hn;
                if (out_seq)
                    out_seq[((size_t)r * Tc + tt) * H_ + j] = hn;
                if (tt == Tc - 1)
                    h_state[(size_t)r * H_ + j] = hn;
            }
        }
        __syncthreads();
        cur ^= 1;
    }
}

// Fused layer-pipelined scan: blocks 0..63 -> layer0 chunk c (4 rows each),
// blocks 64..127 -> layer1 chunk c-1. 84 KB static LDS -> 1 block/CU.
__global__ __launch_bounds__(512) void k_gru_scan_fused(
    const float* __restrict__ gi0, const uint4* __restrict__ wl0,
    const float* __restrict__ bhh0, float* __restrict__ hst0,
    float* __restrict__ h1c,
    const float* __restrict__ gi1, const uint4* __restrict__ wl1,
    const float* __restrict__ bhh1, float* __restrict__ hst1,
    int Tc, int do0, int do1, int init0, int init1)
{
    __shared__ __align__(16) float hbuf[2][4][H_];        // 8 KB
    __shared__ float occupancy_pad[19456];                 // 76 KB -> 1 blk/CU
    if (Tc < 0) {   // never true at runtime; keeps the pad allocated
        occupancy_pad[threadIdx.x] = (float)do0;
        hbuf[0][0][threadIdx.x & 255] = occupancy_pad[(threadIdx.x * 7) & 19455];
    }

    const int blk = blockIdx.x;
    if (blk < 64) {
        if (!do0) return;
        const int b0 = blk * 4;
        gru_scan_core(gi0 + (size_t)b0 * Tc * G3_, wl0, bhh0,
                      hst0 + (size_t)b0 * H_, h1c + (size_t)b0 * Tc * H_,
                      Tc, init0, hbuf);
    } else {
        if (!do1) return;
        const int b0 = (blk - 64) * 4;
        gru_scan_core(gi1 + (size_t)b0 * Tc * G3_, wl1, bhh1,
                      hst1 + (size_t)b0 * H_, nullptr,
                      Tc, init1, hbuf);
    }
}

// ---------------------------------------------------------------------------
__global__ void k_fc(const float* __restrict__ h, const float* __restrict__ Wfc,
                     const float* __restrict__ bfc, float* __restrict__ out)
{
    int idx = blockIdx.x * blockDim.x + threadIdx.x;
    if (idx >= B_ * C_) return;
    int b = idx / C_, c = idx % C_;
    const float* hp = h + (size_t)b * H_;
    const float* wp = Wfc + (size_t)c * H_;
    float s = bfc[c];
#pragma unroll 4
    for (int k = 0; k < H_; k++) s = fmaf(hp[k], wp[k], s);
    out[idx] = s;
}

// ---------------------------------------------------------------------------
extern "C" void kernel_launch(void* const* d_in, const int* in_sizes, int n_in,
                              void* d_out, int out_size, void* d_ws, size_t ws_size,
                              hipStream_t stream)
{
    const float* x    = (const float*)d_in[0];
    const float* Wih0 = (const float*)d_in[1];
    const float* Whh0 = (const float*)d_in[2];
    const float* bih0 = (const float*)d_in[3];
    const float* bhh0 = (const float*)d_in[4];
    const float* Wih1 = (const float*)d_in[5];
    const float* Whh1 = (const float*)d_in[6];
    const float* bih1 = (const float*)d_in[7];
    const float* bhh1 = (const float*)d_in[8];
    const float* Wfc  = (const float*)d_in[9];
    const float* bfc  = (const float*)d_in[10];
    float* out = (float*)d_out;

    const size_t wlBytes = (size_t)48 * 512 * sizeof(uint4);   // 393,216 B

    // ---- largest power-of-two T-chunk that fits ws_size -------------------
    const size_t fixedB = 2 * wlBytes + 2 * (size_t)B_ * H_ * 4 + 8192;
    int Tc = 128, tcShift = 7;
    while (Tc > 1) {
        size_t need = fixedB
                    + 2 * (size_t)B_ * Tc * G3_ * 4    // gi0, gi1 chunks
                    + (size_t)B_ * Tc * H_ * 4;        // h1 chunk
        if (need <= ws_size) break;
        Tc >>= 1; tcShift--;
    }
    const int nChunks = T_ / Tc;

    char* ws = (char*)d_ws;
    size_t off = 0;
    auto alloc = [&](size_t bytes) { char* p = ws + off; off += (bytes + 255) & ~(size_t)255; return p; };
    float* gi0  = (float*)alloc((size_t)B_ * Tc * G3_ * 4);
    float* gi1  = (float*)alloc((size_t)B_ * Tc * G3_ * 4);
    float* h1c  = (float*)alloc((size_t)B_ * Tc * H_ * 4);
    uint4* wl0  = (uint4*)alloc(wlBytes);
    uint4* wl1  = (uint4*)alloc(wlBytes);
    float* hst0 = (float*)alloc((size_t)B_ * H_ * 4);
    float* hst1 = (float*)alloc((size_t)B_ * H_ * 4);

    k_pack_whh<<<48, 512, 0, stream>>>(Whh0, wl0);
    k_pack_whh<<<48, 512, 0, stream>>>(Whh1, wl1);

    const dim3 ggrid(G3_ / 64, (B_ * Tc) / 128);

    // software pipeline: fused launch c runs scan0(c) and scan1(c-1)
    k_gemm_nt_bias<<<ggrid, 256, 0, stream>>>(
        x, (long)T_ * D_, Wih0, bih0, gi0, G3_, D_, tcShift);
    k_gru_scan_fused<<<128, 512, 0, stream>>>(
        gi0, wl0, bhh0, hst0, h1c, gi1, wl1, bhh1, hst1,
        Tc, 1, 0, 1, 0);

    for (int c = 1; c < nChunks; ++c) {
        k_gemm_nt_bias<<<ggrid, 256, 0, stream>>>(
            h1c, (long)Tc * H_, Wih1, bih1, gi1, G3_, H_, tcShift);  // chunk c-1
        k_gemm_nt_bias<<<ggrid, 256, 0, stream>>>(
            x + (size_t)c * Tc * D_, (long)T_ * D_, Wih0, bih0, gi0,
            G3_, D_, tcShift);                                        // chunk c
        k_gru_scan_fused<<<128, 512, 0, stream>>>(
            gi0, wl0, bhh0, hst0, h1c, gi1, wl1, bhh1, hst1,
            Tc, 1, 1, 0, c == 1);
    }

    k_gemm_nt_bias<<<ggrid, 256, 0, stream>>>(
        h1c, (long)Tc * H_, Wih1, bih1, gi1, G3_, H_, tcShift);      // last chunk
    k_gru_scan_fused<<<128, 512, 0, stream>>>(
        gi0, wl0, bhh0, hst0, h1c, gi1, wl1, bhh1, hst1,
        Tc, 0, 1, 0, nChunks == 1);

    k_fc<<<10, 256, 0, stream>>>(hst1, Wfc, bfc, out);
}